// Round 1
// baseline (583.598 us; speedup 1.0000x reference)
//
#include <hip/hip_runtime.h>

#define TABLE_SIZE 4194304
#define NPTS (128*128*128)

// ---------------- Reduction: mean/std over ht[0:3, :] (3*TABLE_SIZE floats) ----

__global__ __launch_bounds__(256) void reduce_partial_kernel(
    const float* __restrict__ ht, double* __restrict__ part, int nblocks)
{
    const long long total = 3LL * TABLE_SIZE;
    double s = 0.0, s2 = 0.0;
    long long stride = (long long)gridDim.x * blockDim.x;
    for (long long i = (long long)blockIdx.x * blockDim.x + threadIdx.x; i < total; i += stride) {
        double v = (double)ht[i];
        s += v;
        s2 += v * v;
    }
    // wave (64-lane) butterfly reduce
    for (int off = 32; off > 0; off >>= 1) {
        s  += __shfl_down(s, off, 64);
        s2 += __shfl_down(s2, off, 64);
    }
    __shared__ double ls[4], ls2[4];
    int wid = threadIdx.x >> 6;
    if ((threadIdx.x & 63) == 0) { ls[wid] = s; ls2[wid] = s2; }
    __syncthreads();
    if (threadIdx.x == 0) {
        double a = 0.0, b = 0.0;
        for (int w = 0; w < 4; ++w) { a += ls[w]; b += ls2[w]; }
        part[blockIdx.x] = a;
        part[nblocks + blockIdx.x] = b;
    }
}

__global__ __launch_bounds__(256) void reduce_final_kernel(
    double* __restrict__ part, int nblocks)
{
    double s = 0.0, s2 = 0.0;
    for (int i = threadIdx.x; i < nblocks; i += blockDim.x) {
        s  += part[i];
        s2 += part[nblocks + i];
    }
    for (int off = 32; off > 0; off >>= 1) {
        s  += __shfl_down(s, off, 64);
        s2 += __shfl_down(s2, off, 64);
    }
    __shared__ double ls[4], ls2[4];
    int wid = threadIdx.x >> 6;
    if ((threadIdx.x & 63) == 0) { ls[wid] = s; ls2[wid] = s2; }
    __syncthreads();
    if (threadIdx.x == 0) {
        double a = 0.0, b = 0.0;
        for (int w = 0; w < 4; ++w) { a += ls[w]; b += ls2[w]; }
        double n = 3.0 * (double)TABLE_SIZE;
        double mean = a / n;
        double var = (b - n * mean * mean) / (n - 1.0);
        part[2 * nblocks]     = mean;
        part[2 * nblocks + 1] = 1.0 / sqrt(var);
    }
}

// ---------------- Main per-point kernel ----------------

__device__ __forceinline__ float sigmoidf_acc(float x) {
    return 1.0f / (1.0f + expf(-x));
}

__global__ __launch_bounds__(256) void HashTableVoxelizedGaussianAdapterModule_86990267613197_kernel(
    const int* __restrict__ coords,
    const float* __restrict__ ht,
    const float* __restrict__ cam,
    const float* __restrict__ farp,
    const int* __restrict__ vsp,
    const double* __restrict__ stats,
    float* __restrict__ out)
{
    int i = blockIdx.x * blockDim.x + threadIdx.x;
    if (i >= NPTS) return;

    int c0 = coords[3 * i + 0];
    int c1 = coords[3 * i + 1];
    int c2 = coords[3 * i + 2];

    unsigned int h = (unsigned int)c0 * 1u
                   ^ (unsigned int)c1 * 2654435761u
                   ^ (unsigned int)c2 * 805459861u;
    int idx = (int)(h & (unsigned int)(TABLE_SIZE - 1));

    float far = farp[0];
    float vs  = (float)vsp[0];           // first 32-bit word (128 either way)
    float scale_fac = 2.0f * far / vs;

    float mean   = (float)stats[0];
    float invstd = (float)stats[1];

    const float* p = ht + idx;

    // dmeans (rows 0..2): normalized * scale_fac/6
    float nf = invstd * (scale_fac / 6.0f);
    float f0 = (p[0 * TABLE_SIZE] - mean) * nf;
    float f1 = (p[1 * TABLE_SIZE] - mean) * nf;
    float f2 = (p[2 * TABLE_SIZE] - mean) * nf;
    // quat (rows 3..6): raw
    float q0 = p[3 * TABLE_SIZE];
    float q1 = p[4 * TABLE_SIZE];
    float q2 = p[5 * TABLE_SIZE];
    float q3 = p[6 * TABLE_SIZE];
    // scale (rows 7..9): sigmoid * scale_fac
    float s0 = sigmoidf_acc(p[7 * TABLE_SIZE]) * scale_fac;
    float s1 = sigmoidf_acc(p[8 * TABLE_SIZE]) * scale_fac;
    float s2 = sigmoidf_acc(p[9 * TABLE_SIZE]) * scale_fac;
    // shs (rows 10..12): sigmoid
    float sh0 = sigmoidf_acc(p[10 * TABLE_SIZE]);
    float sh1 = sigmoidf_acc(p[11 * TABLE_SIZE]);
    float sh2 = sigmoidf_acc(p[12 * TABLE_SIZE]);
    // opac (row 13): sigmoid(x-4)
    float op = sigmoidf_acc(p[13 * TABLE_SIZE] - 4.0f);
    // row 14 (curr) is unused by the output -> skipped.

    // vc = coords/vs * 2*far - far + cam + far/vs
    float k = 2.0f * far / vs;
    float off = -far + far / vs;
    float vcx = (float)c0 * k + off + cam[0];
    float vcy = (float)c1 * k + off + cam[1];
    float vcz = (float)c2 * k + off + cam[2];

    float mx = f0 + vcx;
    float my = f1 + vcy;
    float mz = f2 + vcz;

    // quat -> rotmat (normalized)
    float qn = 1.0f / sqrtf(q0 * q0 + q1 * q1 + q2 * q2 + q3 * q3);
    float r = q0 * qn, x = q1 * qn, y = q2 * qn, z = q3 * qn;

    float R00 = 1.0f - 2.0f * (y * y + z * z);
    float R01 = 2.0f * (x * y - r * z);
    float R02 = 2.0f * (x * z + r * y);
    float R10 = 2.0f * (x * y + r * z);
    float R11 = 1.0f - 2.0f * (x * x + z * z);
    float R12 = 2.0f * (y * z - r * x);
    float R20 = 2.0f * (x * z - r * y);
    float R21 = 2.0f * (y * z + r * x);
    float R22 = 1.0f - 2.0f * (x * x + y * y);

    float L00 = R00 * s0, L01 = R01 * s1, L02 = R02 * s2;
    float L10 = R10 * s0, L11 = R11 * s1, L12 = R12 * s2;
    float L20 = R20 * s0, L21 = R21 * s1, L22 = R22 * s2;

    float c00 = L00 * L00 + L01 * L01 + L02 * L02;
    float c01 = L00 * L10 + L01 * L11 + L02 * L12;
    float c02 = L00 * L20 + L01 * L21 + L02 * L22;
    float c11 = L10 * L10 + L11 * L11 + L12 * L12;
    float c12 = L10 * L20 + L11 * L21 + L12 * L22;
    float c22 = L20 * L20 + L21 * L21 + L22 * L22;

    float4* o = (float4*)(out + 16LL * i);
    o[0] = make_float4(mx, my, mz, c00);
    o[1] = make_float4(c01, c02, c01, c11);
    o[2] = make_float4(c12, c02, c12, c22);
    o[3] = make_float4(sh0, sh1, sh2, op);
}

// ---------------- Launch ----------------

extern "C" void kernel_launch(void* const* d_in, const int* in_sizes, int n_in,
                              void* d_out, int out_size, void* d_ws, size_t ws_size,
                              hipStream_t stream) {
    const int*   coords = (const int*)d_in[0];
    const float* ht     = (const float*)d_in[1];
    const float* cam    = (const float*)d_in[2];
    const float* farp   = (const float*)d_in[3];
    const int*   vsp    = (const int*)d_in[4];
    float* out = (float*)d_out;
    double* ws = (double*)d_ws;

    // choose reduction block count that fits in ws (need 2*nb+2 doubles)
    int nb = 1024;
    size_t need = (2 * (size_t)nb + 2) * sizeof(double);
    if (ws_size < need) {
        size_t cap = ws_size / sizeof(double);
        nb = (int)((cap > 4) ? ((cap - 2) / 2) : 1);
        if (nb < 1) nb = 1;
        if (nb > 1024) nb = 1024;
    }

    reduce_partial_kernel<<<nb, 256, 0, stream>>>(ht, ws, nb);
    reduce_final_kernel<<<1, 256, 0, stream>>>(ws, nb);

    const double* stats = ws + 2 * nb;
    int nblk = (NPTS + 255) / 256;
    HashTableVoxelizedGaussianAdapterModule_86990267613197_kernel<<<nblk, 256, 0, stream>>>(
        coords, ht, cam, farp, vsp, stats, out);
}

// Round 2
// 251.274 us; speedup vs baseline: 2.3226x; 2.3226x over previous
//
#include <hip/hip_runtime.h>

#define TABLE_SIZE 4194304
#define NPTS (128*128*128)

// ---------------- Reduction: mean/std over ht[0:3, :] (3*TABLE_SIZE floats) ----

__global__ __launch_bounds__(256) void reduce_partial_kernel(
    const float4* __restrict__ ht4, double* __restrict__ part, int nblocks)
{
    const int total4 = 3 * TABLE_SIZE / 4;
    double s = 0.0, s2 = 0.0;
    int stride = gridDim.x * blockDim.x;
    for (int i = blockIdx.x * blockDim.x + threadIdx.x; i < total4; i += stride) {
        float4 v = ht4[i];
        double a = (double)v.x, b = (double)v.y, c = (double)v.z, d = (double)v.w;
        s  += a + b + c + d;
        s2 += a * a + b * b + c * c + d * d;
    }
    for (int off = 32; off > 0; off >>= 1) {
        s  += __shfl_down(s, off, 64);
        s2 += __shfl_down(s2, off, 64);
    }
    __shared__ double ls[4], ls2[4];
    int wid = threadIdx.x >> 6;
    if ((threadIdx.x & 63) == 0) { ls[wid] = s; ls2[wid] = s2; }
    __syncthreads();
    if (threadIdx.x == 0) {
        double a = 0.0, b = 0.0;
        for (int w = 0; w < 4; ++w) { a += ls[w]; b += ls2[w]; }
        part[blockIdx.x] = a;
        part[nblocks + blockIdx.x] = b;
    }
}

__global__ __launch_bounds__(256) void reduce_final_kernel(
    double* __restrict__ part, int nblocks)
{
    double s = 0.0, s2 = 0.0;
    for (int i = threadIdx.x; i < nblocks; i += blockDim.x) {
        s  += part[i];
        s2 += part[nblocks + i];
    }
    for (int off = 32; off > 0; off >>= 1) {
        s  += __shfl_down(s, off, 64);
        s2 += __shfl_down(s2, off, 64);
    }
    __shared__ double ls[4], ls2[4];
    int wid = threadIdx.x >> 6;
    if ((threadIdx.x & 63) == 0) { ls[wid] = s; ls2[wid] = s2; }
    __syncthreads();
    if (threadIdx.x == 0) {
        double a = 0.0, b = 0.0;
        for (int w = 0; w < 4; ++w) { a += ls[w]; b += ls2[w]; }
        double n = 3.0 * (double)TABLE_SIZE;
        double mean = a / n;
        double var = (b - n * mean * mean) / (n - 1.0);
        part[2 * nblocks]     = mean;
        part[2 * nblocks + 1] = 1.0 / sqrt(var);
    }
}

__device__ __forceinline__ float sigmoidf_acc(float x) {
    return 1.0f / (1.0f + expf(-x));
}

// ---------------- Pre-pass: transpose + activate + fold covariance ----------------
// Entry j -> 16 floats at tab[4*j .. 4*j+3]:
//   [f0,f1,f2,c00] [c01,c02,c11,c12] [c22,sh0,sh1,sh2] [op,0,0,0]

__global__ __launch_bounds__(256) void transpose_activate_kernel(
    const float* __restrict__ ht,
    const float* __restrict__ farp,
    const int* __restrict__ vsp,
    const double* __restrict__ stats,
    float4* __restrict__ tab)
{
    int j = blockIdx.x * blockDim.x + threadIdx.x;   // exact grid: TABLE_SIZE/256

    float far = farp[0];
    float vs  = (float)vsp[0];
    float scale_fac = 2.0f * far / vs;
    float mean   = (float)stats[0];
    float invstd = (float)stats[1];

    const float* p = ht + j;
    float nf = invstd * (scale_fac / 6.0f);
    float f0 = (p[0 * TABLE_SIZE] - mean) * nf;
    float f1 = (p[1 * TABLE_SIZE] - mean) * nf;
    float f2 = (p[2 * TABLE_SIZE] - mean) * nf;
    float q0 = p[3 * TABLE_SIZE];
    float q1 = p[4 * TABLE_SIZE];
    float q2 = p[5 * TABLE_SIZE];
    float q3 = p[6 * TABLE_SIZE];
    float s0 = sigmoidf_acc(p[7 * TABLE_SIZE]) * scale_fac;
    float s1 = sigmoidf_acc(p[8 * TABLE_SIZE]) * scale_fac;
    float s2 = sigmoidf_acc(p[9 * TABLE_SIZE]) * scale_fac;
    float sh0 = sigmoidf_acc(p[10 * TABLE_SIZE]);
    float sh1 = sigmoidf_acc(p[11 * TABLE_SIZE]);
    float sh2 = sigmoidf_acc(p[12 * TABLE_SIZE]);
    float op  = sigmoidf_acc(p[13 * TABLE_SIZE] - 4.0f);

    float qn = 1.0f / sqrtf(q0 * q0 + q1 * q1 + q2 * q2 + q3 * q3);
    float r = q0 * qn, x = q1 * qn, y = q2 * qn, z = q3 * qn;

    float R00 = 1.0f - 2.0f * (y * y + z * z);
    float R01 = 2.0f * (x * y - r * z);
    float R02 = 2.0f * (x * z + r * y);
    float R10 = 2.0f * (x * y + r * z);
    float R11 = 1.0f - 2.0f * (x * x + z * z);
    float R12 = 2.0f * (y * z - r * x);
    float R20 = 2.0f * (x * z - r * y);
    float R21 = 2.0f * (y * z + r * x);
    float R22 = 1.0f - 2.0f * (x * x + y * y);

    float L00 = R00 * s0, L01 = R01 * s1, L02 = R02 * s2;
    float L10 = R10 * s0, L11 = R11 * s1, L12 = R12 * s2;
    float L20 = R20 * s0, L21 = R21 * s1, L22 = R22 * s2;

    float c00 = L00 * L00 + L01 * L01 + L02 * L02;
    float c01 = L00 * L10 + L01 * L11 + L02 * L12;
    float c02 = L00 * L20 + L01 * L21 + L02 * L22;
    float c11 = L10 * L10 + L11 * L11 + L12 * L12;
    float c12 = L10 * L20 + L11 * L21 + L12 * L22;
    float c22 = L20 * L20 + L21 * L21 + L22 * L22;

    tab[4 * j + 0] = make_float4(f0, f1, f2, c00);
    tab[4 * j + 1] = make_float4(c01, c02, c11, c12);
    tab[4 * j + 2] = make_float4(c22, sh0, sh1, sh2);
    tab[4 * j + 3] = make_float4(op, 0.0f, 0.0f, 0.0f);
}

// ---------------- Main per-point kernel (gather path) ----------------

__global__ __launch_bounds__(256) void HashTableVoxelizedGaussianAdapterModule_86990267613197_kernel(
    const int* __restrict__ coords,
    const float4* __restrict__ tab,
    const float* __restrict__ cam,
    const float* __restrict__ farp,
    const int* __restrict__ vsp,
    float4* __restrict__ out)
{
    int i = blockIdx.x * blockDim.x + threadIdx.x;   // exact grid: NPTS/256

    int c0 = coords[3 * i + 0];
    int c1 = coords[3 * i + 1];
    int c2 = coords[3 * i + 2];

    unsigned int h = (unsigned int)c0 * 1u
                   ^ (unsigned int)c1 * 2654435761u
                   ^ (unsigned int)c2 * 805459861u;
    int idx = (int)(h & (unsigned int)(TABLE_SIZE - 1));

    float4 e0 = tab[4 * idx + 0];
    float4 e1 = tab[4 * idx + 1];
    float4 e2 = tab[4 * idx + 2];
    float4 e3 = tab[4 * idx + 3];

    float far = farp[0];
    float vs  = (float)vsp[0];
    float k   = 2.0f * far / vs;
    float off = -far + far / vs;
    float vcx = (float)c0 * k + off + cam[0];
    float vcy = (float)c1 * k + off + cam[1];
    float vcz = (float)c2 * k + off + cam[2];

    out[4 * i + 0] = make_float4(e0.x + vcx, e0.y + vcy, e0.z + vcz, e0.w);
    out[4 * i + 1] = make_float4(e1.x, e1.y, e1.x, e1.z);   // c01 c02 c01 c11
    out[4 * i + 2] = make_float4(e1.w, e1.y, e1.w, e2.x);   // c12 c02 c12 c22
    out[4 * i + 3] = make_float4(e2.y, e2.z, e2.w, e3.x);   // sh0 sh1 sh2 op
}

// ---------------- Fallback direct kernel (if ws too small) ----------------

__global__ __launch_bounds__(256) void direct_kernel(
    const int* __restrict__ coords,
    const float* __restrict__ ht,
    const float* __restrict__ cam,
    const float* __restrict__ farp,
    const int* __restrict__ vsp,
    const double* __restrict__ stats,
    float* __restrict__ out)
{
    int i = blockIdx.x * blockDim.x + threadIdx.x;
    if (i >= NPTS) return;

    int c0 = coords[3 * i + 0];
    int c1 = coords[3 * i + 1];
    int c2 = coords[3 * i + 2];

    unsigned int h = (unsigned int)c0 * 1u
                   ^ (unsigned int)c1 * 2654435761u
                   ^ (unsigned int)c2 * 805459861u;
    int idx = (int)(h & (unsigned int)(TABLE_SIZE - 1));

    float far = farp[0];
    float vs  = (float)vsp[0];
    float scale_fac = 2.0f * far / vs;
    float mean   = (float)stats[0];
    float invstd = (float)stats[1];

    const float* p = ht + idx;
    float nf = invstd * (scale_fac / 6.0f);
    float f0 = (p[0 * TABLE_SIZE] - mean) * nf;
    float f1 = (p[1 * TABLE_SIZE] - mean) * nf;
    float f2 = (p[2 * TABLE_SIZE] - mean) * nf;
    float q0 = p[3 * TABLE_SIZE];
    float q1 = p[4 * TABLE_SIZE];
    float q2 = p[5 * TABLE_SIZE];
    float q3 = p[6 * TABLE_SIZE];
    float s0 = sigmoidf_acc(p[7 * TABLE_SIZE]) * scale_fac;
    float s1 = sigmoidf_acc(p[8 * TABLE_SIZE]) * scale_fac;
    float s2 = sigmoidf_acc(p[9 * TABLE_SIZE]) * scale_fac;
    float sh0 = sigmoidf_acc(p[10 * TABLE_SIZE]);
    float sh1 = sigmoidf_acc(p[11 * TABLE_SIZE]);
    float sh2 = sigmoidf_acc(p[12 * TABLE_SIZE]);
    float op  = sigmoidf_acc(p[13 * TABLE_SIZE] - 4.0f);

    float k = 2.0f * far / vs;
    float off = -far + far / vs;
    float vcx = (float)c0 * k + off + cam[0];
    float vcy = (float)c1 * k + off + cam[1];
    float vcz = (float)c2 * k + off + cam[2];

    float qn = 1.0f / sqrtf(q0 * q0 + q1 * q1 + q2 * q2 + q3 * q3);
    float r = q0 * qn, x = q1 * qn, y = q2 * qn, z = q3 * qn;

    float R00 = 1.0f - 2.0f * (y * y + z * z);
    float R01 = 2.0f * (x * y - r * z);
    float R02 = 2.0f * (x * z + r * y);
    float R10 = 2.0f * (x * y + r * z);
    float R11 = 1.0f - 2.0f * (x * x + z * z);
    float R12 = 2.0f * (y * z - r * x);
    float R20 = 2.0f * (x * z - r * y);
    float R21 = 2.0f * (y * z + r * x);
    float R22 = 1.0f - 2.0f * (x * x + y * y);

    float L00 = R00 * s0, L01 = R01 * s1, L02 = R02 * s2;
    float L10 = R10 * s0, L11 = R11 * s1, L12 = R12 * s2;
    float L20 = R20 * s0, L21 = R21 * s1, L22 = R22 * s2;

    float c00 = L00 * L00 + L01 * L01 + L02 * L02;
    float c01 = L00 * L10 + L01 * L11 + L02 * L12;
    float c02 = L00 * L20 + L01 * L21 + L02 * L22;
    float c11 = L10 * L10 + L11 * L11 + L12 * L12;
    float c12 = L10 * L20 + L11 * L21 + L12 * L22;
    float c22 = L20 * L20 + L21 * L21 + L22 * L22;

    float4* o = (float4*)(out + 16LL * i);
    o[0] = make_float4(f0 + vcx, f1 + vcy, f2 + vcz, c00);
    o[1] = make_float4(c01, c02, c01, c11);
    o[2] = make_float4(c12, c02, c12, c22);
    o[3] = make_float4(sh0, sh1, sh2, op);
}

// ---------------- Launch ----------------

extern "C" void kernel_launch(void* const* d_in, const int* in_sizes, int n_in,
                              void* d_out, int out_size, void* d_ws, size_t ws_size,
                              hipStream_t stream) {
    const int*   coords = (const int*)d_in[0];
    const float* ht     = (const float*)d_in[1];
    const float* cam    = (const float*)d_in[2];
    const float* farp   = (const float*)d_in[3];
    const int*   vsp    = (const int*)d_in[4];
    float* out = (float*)d_out;

    const int nb = 1024;                       // reduction blocks
    const size_t red_bytes = 32768;            // reserve (needs 2*nb+2 doubles = 16.4 KB)
    const size_t tab_bytes = (size_t)TABLE_SIZE * 16 * sizeof(float);   // 268.4 MB

    double* ws = (double*)d_ws;

    reduce_partial_kernel<<<nb, 256, 0, stream>>>((const float4*)ht, ws, nb);
    reduce_final_kernel<<<1, 256, 0, stream>>>(ws, nb);
    const double* stats = ws + 2 * nb;

    if (ws_size >= red_bytes + tab_bytes) {
        float4* tab = (float4*)((char*)d_ws + red_bytes);
        transpose_activate_kernel<<<TABLE_SIZE / 256, 256, 0, stream>>>(
            ht, farp, vsp, stats, tab);
        HashTableVoxelizedGaussianAdapterModule_86990267613197_kernel<<<NPTS / 256, 256, 0, stream>>>(
            coords, tab, cam, farp, vsp, (float4*)out);
    } else {
        direct_kernel<<<(NPTS + 255) / 256, 256, 0, stream>>>(
            coords, ht, cam, farp, vsp, stats, out);
    }
}